// Round 5
// baseline (256.533 us; speedup 1.0000x reference)
//
#include <hip/hip_runtime.h>

typedef __bf16 bf16x8 __attribute__((ext_vector_type(8)));
typedef float f32x4 __attribute__((ext_vector_type(4)));

#define SCALE_F 0.014731391274719738f   /* 1/sqrt(9*512) */
#define SCALE2_F 2.170138888888889e-4f  /* 1/4608 */

__device__ __forceinline__ ushort f2bf(float f) {
    uint x = __float_as_uint(f);
    uint r = (x + 0x7fffu + ((x >> 16) & 1u)) >> 16;
    return (ushort)r;
}

__device__ __forceinline__ void async_cp16(const void* g, void* l) {
    __builtin_amdgcn_global_load_lds(
        (const __attribute__((address_space(1))) void*)g,
        (__attribute__((address_space(3))) void*)l, 16, 0, 0);
}

// ---------------- prep kernels (unchanged) ----------------

__global__ void k_q(const float* __restrict__ kern, float* __restrict__ Q) {
    int idx = blockIdx.x * 256 + threadIdx.x;
    float s = 0.f;
#pragma unroll
    for (int t = 0; t < 9; ++t) { float v = kern[t * 262144 + idx]; s += v * v; }
    Q[idx] = s * SCALE2_F;
}

__global__ void k_sigma(const float* __restrict__ style, const float* __restrict__ Q,
                        float* __restrict__ sig) {
    __shared__ float s2[512];
    int b = blockIdx.x, t = threadIdx.x;
    float s = style[b * 512 + t];
    s2[t] = s * s;
    __syncthreads();
    float acc = 0.f;
#pragma unroll 8
    for (int ci = 0; ci < 512; ++ci) acc += s2[ci] * Q[ci * 512 + t];
    sig[b * 512 + t] = rsqrtf(acc + 1e-8f);
}

__global__ void k_wt(const float* __restrict__ kern, const float* __restrict__ style,
                     const float* __restrict__ sig, ushort* __restrict__ wT) {
    __shared__ ushort tile[64 * 65];
    int b = blockIdx.z, tap = blockIdx.y;
    int ci0 = (blockIdx.x >> 3) << 6, co0 = (blockIdx.x & 7) << 6;
    int t = threadIdx.x;
    int col = t & 63, rq = t >> 6;
#pragma unroll
    for (int r = 0; r < 16; ++r) {
        int ci_l = r * 4 + rq;
        float v = kern[(size_t)(tap * 512 + ci0 + ci_l) * 512 + co0 + col];
        float val = SCALE_F * v * style[b * 512 + ci0 + ci_l] * sig[b * 512 + co0 + col];
        tile[ci_l * 65 + col] = f2bf(val);
    }
    __syncthreads();
#pragma unroll
    for (int r = 0; r < 4; ++r) {
        int q = r * 256 + t;
        int co_l = q >> 4, ciq = (q & 15) << 2;
        uint lo = (uint)tile[ciq * 65 + co_l] | ((uint)tile[(ciq + 1) * 65 + co_l] << 16);
        uint hi = (uint)tile[(ciq + 2) * 65 + co_l] | ((uint)tile[(ciq + 3) * 65 + co_l] << 16);
        *(uint2*)(&wT[((size_t)(b * 9 + tap) * 512 + co0 + co_l) * 512 + ci0 + ciq]) =
            make_uint2(lo, hi);
    }
}

__global__ void k_xpad(const float* __restrict__ x, ushort* __restrict__ xp) {
    int idx = blockIdx.x * 256 + threadIdx.x;
    int pos = idx >> 6, e = idx & 63;
    int b = pos / 4356, rem = pos - b * 4356;
    int hp = rem / 66, wp = rem - hp * 66;
    int ci0 = e << 3;
    uint4 o = make_uint4(0u, 0u, 0u, 0u);
    if (hp >= 1 && hp <= 64 && wp >= 1 && wp <= 64) {
        const float4* s =
            (const float4*)(x + (((size_t)(b * 4096 + (hp - 1) * 64 + (wp - 1))) << 9) + ci0);
        float4 v0 = s[0], v1 = s[1];
        o.x = (uint)f2bf(v0.x) | ((uint)f2bf(v0.y) << 16);
        o.y = (uint)f2bf(v0.z) | ((uint)f2bf(v0.w) << 16);
        o.z = (uint)f2bf(v1.x) | ((uint)f2bf(v1.y) << 16);
        o.w = (uint)f2bf(v1.z) | ((uint)f2bf(v1.w) << 16);
    }
    *(uint4*)(xp + (((size_t)pos) << 9) + ci0) = o;
}

// ---------------- main conv: 256x256 tile, BK=64, 8 waves ----------------
// R5: B fragments bypass LDS -> prefetched from global (L1/L2-resident panel)
// into register banks one K-tile ahead. LDS = A only (2 x 32KB double buffer).
// LDS traffic/K-tile: 256KB -> 160KB (below MFMA floor). One barrier per K-tile.
__global__ __launch_bounds__(512, 2) void conv_mfma(const ushort* __restrict__ xpad,
                                                    const ushort* __restrict__ wT,
                                                    float* __restrict__ out) {
    extern __shared__ char lds[];   // A: 2 buffers x 32768 B

    // XCD swizzle: chunk of 32 contiguous logical ids (= one batch b) per XCD.
    const int wg = blockIdx.x;                      // 0..255
    const int swz = (wg & 7) * 32 + (wg >> 3);      // bijective (256 % 8 == 0)
    const int mt = swz & 15;
    const int nt = (swz >> 4) & 1;
    const int b = swz >> 5;

    const int tid = threadIdx.x;
    const int l = tid & 63, wv = tid >> 6;
    const int wm = (wv >> 2) * 128;
    const int wn = (wv & 3) * 64;
    const int ha = wv >> 2;          // A half this wave reads
    const int hb = (wv & 3) >> 1;    // B half this wave reads

    // A staging geometry: lane l covers row (l>>3) of an 8-row group, stored chunk l&7
    const int rl = l >> 3;
    const int g = (l & 7) ^ rl;      // data chunk pre-swizzle
    const ushort* baseA[2][2];
    int ldsoff[2][2];
#pragma unroll
    for (int h = 0; h < 2; ++h)
#pragma unroll
        for (int i = 0; i < 2; ++i) {
            int rloc = wv * 16 + i * 8 + rl;
            int R = h * 128 + rloc;
            baseA[h][i] = xpad + ((size_t)((b * 66 + mt * 4 + (R >> 6)) * 66 + (R & 63))) * 512 + g * 8;
            ldsoff[h][i] = (h * 128 + wv * 16 + i * 8) * 128;
        }

    const int frow = l & 15;
    const int fchunk_base = l >> 4;   // 0..3
    const int fxor = l & 7;

    // B global fragment bases (per ni); row-major wT[b][tap][co][ci]
    const char* bbase[4];
#pragma unroll
    for (int ni = 0; ni < 4; ++ni) {
        int row = nt * 256 + hb * 128 + (wn & 64) + ni * 16 + frow;
        bbase[ni] = (const char*)(wT + ((size_t)(b * 9 * 512) + row) * 512) +
                    fchunk_base * 16;
    }

    auto offA = [](int t) -> int {
        int tap = t >> 3;
        int ky = (tap * 11) >> 5;
        int kx = tap - ky * 3;
        return (ky * 66 + kx) * 512 + ((t & 7) << 6);
    };
    // byte offset into wT for K-tile t
    auto offBb = [](int t) -> int { return (t >> 3) * 524288 + ((t & 7) << 7); };

    auto stageA = [&](int t, int buf) {
        int oA = offA(t);
        char* Ab = lds + buf * 32768;
#pragma unroll
        for (int h = 0; h < 2; ++h)
#pragma unroll
            for (int i = 0; i < 2; ++i)
                async_cp16(baseA[h][i] + oA, Ab + ldsoff[h][i]);
    };

    auto loadB = [&](bf16x8 (&bq)[4][2], int t) {
        const int off = offBb(t);
#pragma unroll
        for (int ni = 0; ni < 4; ++ni)
#pragma unroll
            for (int kk = 0; kk < 2; ++kk)
                bq[ni][kk] = *(const bf16x8*)(bbase[ni] + off + kk * 64);
    };

    f32x4 acc[8][4];
#pragma unroll
    for (int mi = 0; mi < 8; ++mi)
#pragma unroll
        for (int ni = 0; ni < 4; ++ni) acc[mi][ni] = (f32x4){0.f, 0.f, 0.f, 0.f};

    auto region = [&](const char* aB, bf16x8 (&bq)[4][2]) {
#pragma unroll
        for (int q = 0; q < 4; ++q) {
            bf16x8 aq[2][2];
#pragma unroll
            for (int m2 = 0; m2 < 2; ++m2)
#pragma unroll
                for (int kk = 0; kk < 2; ++kk) {
                    int r = (2 * q + m2) * 16 + frow;
                    aq[m2][kk] = *(const bf16x8*)(aB + r * 128 +
                                                  (((kk * 4 + fchunk_base) ^ fxor) * 16));
                }
            __builtin_amdgcn_s_setprio(1);
#pragma unroll
            for (int kk = 0; kk < 2; ++kk)
#pragma unroll
                for (int ni = 0; ni < 4; ++ni)
#pragma unroll
                    for (int m2 = 0; m2 < 2; ++m2)
                        acc[2 * q + m2][ni] = __builtin_amdgcn_mfma_f32_16x16x32_bf16(
                            aq[m2][kk], bq[ni][kk], acc[2 * q + m2][ni], 0, 0, 0);
            __builtin_amdgcn_s_setprio(0);
        }
    };

    auto fence = [&]() {
        asm volatile("s_waitcnt vmcnt(0)" ::: "memory");
        __builtin_amdgcn_sched_barrier(0);
        __builtin_amdgcn_s_barrier();
        __builtin_amdgcn_sched_barrier(0);
    };

    bf16x8 bq0[4][2], bq1[4][2];

    // prologue: A tile0 -> buf0, B tile0 -> bank0
    stageA(0, 0);
    loadB(bq0, 0);
    fence();

    const char* aB0 = lds + ha * 16384;
    const char* aB1 = lds + 32768 + ha * 16384;

#pragma unroll 1
    for (int GG = 0; GG < 36; ++GG) {
        const int G0 = 2 * GG;
        // region G0 (even): A buf0 + bq0; prefetch G0+1 into buf1/bq1
        loadB(bq1, G0 + 1);
        stageA(G0 + 1, 1);
        region(aB0, bq0);
        fence();
        // region G0+1 (odd): A buf1 + bq1; prefetch G0+2 into buf0/bq0
        if (GG < 35) {
            loadB(bq0, G0 + 2);
            stageA(G0 + 2, 0);
        }
        region(aB1, bq1);
        if (GG < 35) fence();
    }

    // epilogue: D[(l>>4)*4+r][l&15] per 16x16 fragment
#pragma unroll
    for (int mi = 0; mi < 8; ++mi) {
#pragma unroll
        for (int ni = 0; ni < 4; ++ni) {
#pragma unroll
            for (int r = 0; r < 4; ++r) {
                int m = mt * 256 + wm + mi * 16 + (l >> 4) * 4 + r;
                int co = nt * 256 + wn + ni * 16 + (l & 15);
                out[(((size_t)(b * 4096 + m)) << 9) + co] = acc[mi][ni][r];
            }
        }
    }
}

// ---------------- launch ----------------

extern "C" void kernel_launch(void* const* d_in, const int* in_sizes, int n_in,
                              void* d_out, int out_size, void* d_ws, size_t ws_size,
                              hipStream_t stream) {
    const float* x = (const float*)d_in[0];
    const float* style = (const float*)d_in[1];
    const float* kern = (const float*)d_in[2];
    float* out = (float*)d_out;

    char* ws = (char*)d_ws;
    ushort* xpad = (ushort*)ws;                                // 35,684,352 B
    ushort* wT = (ushort*)(ws + 35684352);                     // 37,748,736 B
    float* Q = (float*)(ws + 35684352 + 37748736);             // 1,048,576 B
    float* sig = (float*)(ws + 35684352 + 37748736 + 1048576); // 16,384 B

    (void)hipFuncSetAttribute((const void*)conv_mfma,
                              hipFuncAttributeMaxDynamicSharedMemorySize, 65536);

    k_q<<<1024, 256, 0, stream>>>(kern, Q);
    k_sigma<<<8, 512, 0, stream>>>(style, Q, sig);
    k_wt<<<dim3(64, 9, 8), 256, 0, stream>>>(kern, style, sig, wT);
    k_xpad<<<8712, 256, 0, stream>>>(x, xpad);
    conv_mfma<<<256, 512, 65536, stream>>>(xpad, wT, out);
}

// Round 6
// 239.983 us; speedup vs baseline: 1.0690x; 1.0690x over previous
//
#include <hip/hip_runtime.h>

typedef __bf16 bf16x8 __attribute__((ext_vector_type(8)));
typedef float f32x4 __attribute__((ext_vector_type(4)));

#define SCALE_F 0.014731391274719738f   /* 1/sqrt(9*512) */
#define SCALE2_F 2.170138888888889e-4f  /* 1/4608 */

__device__ __forceinline__ ushort f2bf(float f) {
    uint x = __float_as_uint(f);
    uint r = (x + 0x7fffu + ((x >> 16) & 1u)) >> 16;
    return (ushort)r;
}

__device__ __forceinline__ void async_cp16(const void* g, void* l) {
    __builtin_amdgcn_global_load_lds(
        (const __attribute__((address_space(1))) void*)g,
        (__attribute__((address_space(3))) void*)l, 16, 0, 0);
}

// asm global loads: compiler does NOT track these in vmcnt -> no implicit waits.
// Correctness: our region-end s_waitcnt vmcnt(0) fence (volatile asm) drains them
// before the next region's MFMAs read the destination registers.
__device__ __forceinline__ void gload16_0(bf16x8& d, uint64_t a) {
    asm volatile("global_load_dwordx4 %0, %1, off" : "=v"(d) : "v"(a));
}
__device__ __forceinline__ void gload16_64(bf16x8& d, uint64_t a) {
    asm volatile("global_load_dwordx4 %0, %1, off offset:64" : "=v"(d) : "v"(a));
}

// ---------------- prep kernels (unchanged) ----------------

__global__ void k_q(const float* __restrict__ kern, float* __restrict__ Q) {
    int idx = blockIdx.x * 256 + threadIdx.x;
    float s = 0.f;
#pragma unroll
    for (int t = 0; t < 9; ++t) { float v = kern[t * 262144 + idx]; s += v * v; }
    Q[idx] = s * SCALE2_F;
}

__global__ void k_sigma(const float* __restrict__ style, const float* __restrict__ Q,
                        float* __restrict__ sig) {
    __shared__ float s2[512];
    int b = blockIdx.x, t = threadIdx.x;
    float s = style[b * 512 + t];
    s2[t] = s * s;
    __syncthreads();
    float acc = 0.f;
#pragma unroll 8
    for (int ci = 0; ci < 512; ++ci) acc += s2[ci] * Q[ci * 512 + t];
    sig[b * 512 + t] = rsqrtf(acc + 1e-8f);
}

__global__ void k_wt(const float* __restrict__ kern, const float* __restrict__ style,
                     const float* __restrict__ sig, ushort* __restrict__ wT) {
    __shared__ ushort tile[64 * 65];
    int b = blockIdx.z, tap = blockIdx.y;
    int ci0 = (blockIdx.x >> 3) << 6, co0 = (blockIdx.x & 7) << 6;
    int t = threadIdx.x;
    int col = t & 63, rq = t >> 6;
#pragma unroll
    for (int r = 0; r < 16; ++r) {
        int ci_l = r * 4 + rq;
        float v = kern[(size_t)(tap * 512 + ci0 + ci_l) * 512 + co0 + col];
        float val = SCALE_F * v * style[b * 512 + ci0 + ci_l] * sig[b * 512 + co0 + col];
        tile[ci_l * 65 + col] = f2bf(val);
    }
    __syncthreads();
#pragma unroll
    for (int r = 0; r < 4; ++r) {
        int q = r * 256 + t;
        int co_l = q >> 4, ciq = (q & 15) << 2;
        uint lo = (uint)tile[ciq * 65 + co_l] | ((uint)tile[(ciq + 1) * 65 + co_l] << 16);
        uint hi = (uint)tile[(ciq + 2) * 65 + co_l] | ((uint)tile[(ciq + 3) * 65 + co_l] << 16);
        *(uint2*)(&wT[((size_t)(b * 9 + tap) * 512 + co0 + co_l) * 512 + ci0 + ciq]) =
            make_uint2(lo, hi);
    }
}

__global__ void k_xpad(const float* __restrict__ x, ushort* __restrict__ xp) {
    int idx = blockIdx.x * 256 + threadIdx.x;
    int pos = idx >> 6, e = idx & 63;
    int b = pos / 4356, rem = pos - b * 4356;
    int hp = rem / 66, wp = rem - hp * 66;
    int ci0 = e << 3;
    uint4 o = make_uint4(0u, 0u, 0u, 0u);
    if (hp >= 1 && hp <= 64 && wp >= 1 && wp <= 64) {
        const float4* s =
            (const float4*)(x + (((size_t)(b * 4096 + (hp - 1) * 64 + (wp - 1))) << 9) + ci0);
        float4 v0 = s[0], v1 = s[1];
        o.x = (uint)f2bf(v0.x) | ((uint)f2bf(v0.y) << 16);
        o.y = (uint)f2bf(v0.z) | ((uint)f2bf(v0.w) << 16);
        o.z = (uint)f2bf(v1.x) | ((uint)f2bf(v1.y) << 16);
        o.w = (uint)f2bf(v1.z) | ((uint)f2bf(v1.w) << 16);
    }
    *(uint4*)(xp + (((size_t)pos) << 9) + ci0) = o;
}

// ---------------- main conv: 256x256 tile, BK=64, 8 waves ----------------
// R6 = R4 structure (one barrier per K-tile, A double-buffered in 64KB LDS)
// but B fragments prefetched one K-tile ahead into register banks via
// volatile-asm global_load_dwordx4 (no compiler-inserted waits; our fence's
// vmcnt(0) is the only synchronization). LDS traffic 256KB -> 160KB per K-tile.
__global__ __launch_bounds__(512, 2) void conv_mfma(const ushort* __restrict__ xpad,
                                                    const ushort* __restrict__ wT,
                                                    float* __restrict__ out) {
    extern __shared__ char lds[];   // A: 2 buffers x 32768 B

    const int wg = blockIdx.x;                      // 0..255
    const int swz = (wg & 7) * 32 + (wg >> 3);      // bijective XCD swizzle
    const int mt = swz & 15;
    const int nt = (swz >> 4) & 1;
    const int b = swz >> 5;

    const int tid = threadIdx.x;
    const int l = tid & 63, wv = tid >> 6;
    const int wm = (wv >> 2) * 128;
    const int wn = (wv & 3) * 64;
    const int ha = wv >> 2;          // A half this wave reads
    const int hb = (wv & 3) >> 1;    // B half this wave reads

    // A staging geometry (pre-swizzled global source, XOR-swizzled LDS reads)
    const int rl = l >> 3;
    const int g = (l & 7) ^ rl;
    const ushort* baseA[2][2];
    int ldsoff[2][2];
#pragma unroll
    for (int h = 0; h < 2; ++h)
#pragma unroll
        for (int i = 0; i < 2; ++i) {
            int rloc = wv * 16 + i * 8 + rl;
            int R = h * 128 + rloc;
            baseA[h][i] = xpad + ((size_t)((b * 66 + mt * 4 + (R >> 6)) * 66 + (R & 63))) * 512 + g * 8;
            ldsoff[h][i] = (h * 128 + wv * 16 + i * 8) * 128;
        }

    const int frow = l & 15;
    const int fchunk_base = l >> 4;   // 0..3
    const int fxor = l & 7;

    // B global addresses (per ni), advanced per K-tile. Row-major wT[b][tap][co][ci].
    uint64_t addrB[4];
#pragma unroll
    for (int ni = 0; ni < 4; ++ni) {
        int co = nt * 256 + hb * 128 + (wn & 64) + ni * 16 + frow;
        addrB[ni] = (uint64_t)(const char*)wT +
                    ((uint64_t)((size_t)b * 4608 + co)) * 1024 + (uint64_t)(fchunk_base * 16);
    }

    auto offA = [](int t) -> int {
        int tap = t >> 3;
        int ky = (tap * 11) >> 5;
        int kx = tap - ky * 3;
        return (ky * 66 + kx) * 512 + ((t & 7) << 6);
    };

    auto stageA = [&](int t, int buf) {
        int oA = offA(t);
        char* Ab = lds + buf * 32768;
#pragma unroll
        for (int h = 0; h < 2; ++h)
#pragma unroll
            for (int i = 0; i < 2; ++i)
                async_cp16(baseA[h][i] + oA, Ab + ldsoff[h][i]);
    };

    // issue 8 asm loads for K-tile currently addressed, then advance addrs past tile t
    auto loadB = [&](bf16x8 (&bq)[4][2]) {
#pragma unroll
        for (int ni = 0; ni < 4; ++ni) {
            gload16_0(bq[ni][0], addrB[ni]);
            gload16_64(bq[ni][1], addrB[ni]);
        }
    };
    auto advB = [&](int t) {   // t = tile just loaded
        uint64_t d = ((t & 7) == 7) ? (uint64_t)(524288 - 896) : (uint64_t)128;
#pragma unroll
        for (int ni = 0; ni < 4; ++ni) addrB[ni] += d;
    };

    f32x4 acc[8][4];
#pragma unroll
    for (int mi = 0; mi < 8; ++mi)
#pragma unroll
        for (int ni = 0; ni < 4; ++ni) acc[mi][ni] = (f32x4){0.f, 0.f, 0.f, 0.f};

    auto region = [&](const char* aB, bf16x8 (&bq)[4][2]) {
#pragma unroll
        for (int q = 0; q < 4; ++q) {
            bf16x8 aq[2][2];
#pragma unroll
            for (int m2 = 0; m2 < 2; ++m2)
#pragma unroll
                for (int kk = 0; kk < 2; ++kk) {
                    int r = (2 * q + m2) * 16 + frow;
                    aq[m2][kk] = *(const bf16x8*)(aB + r * 128 +
                                                  (((kk * 4 + fchunk_base) ^ fxor) * 16));
                }
            __builtin_amdgcn_s_setprio(1);
#pragma unroll
            for (int kk = 0; kk < 2; ++kk)
#pragma unroll
                for (int ni = 0; ni < 4; ++ni)
#pragma unroll
                    for (int m2 = 0; m2 < 2; ++m2)
                        acc[2 * q + m2][ni] = __builtin_amdgcn_mfma_f32_16x16x32_bf16(
                            aq[m2][kk], bq[ni][kk], acc[2 * q + m2][ni], 0, 0, 0);
            __builtin_amdgcn_s_setprio(0);
        }
    };

    auto fence = [&]() {
        asm volatile("s_waitcnt vmcnt(0)" ::: "memory");
        __builtin_amdgcn_sched_barrier(0);
        __builtin_amdgcn_s_barrier();
        __builtin_amdgcn_sched_barrier(0);
    };

    bf16x8 bq0[4][2], bq1[4][2];

    // prologue: A tile0 -> buf0, B tile0 -> bank0 (asm loads), drain, barrier
    stageA(0, 0);
    loadB(bq0);
    advB(0);
    fence();

    const char* aB0 = lds + ha * 16384;
    const char* aB1 = lds + 32768 + ha * 16384;

#pragma unroll 1
    for (int GG = 0; GG < 36; ++GG) {
        const int G0 = 2 * GG;
        // even region: compute tile G0 (buf0,bq0); prefetch tile G0+1 (buf1,bq1)
        loadB(bq1);
        advB(G0 + 1);
        stageA(G0 + 1, 1);
        __builtin_amdgcn_sched_barrier(0);   // pin early issue of prefetch
        region(aB0, bq0);
        fence();
        // odd region: compute tile G0+1 (buf1,bq1); prefetch tile G0+2 (buf0,bq0)
        if (GG < 35) {
            loadB(bq0);
            advB(G0 + 2);
            stageA(G0 + 2, 0);
            __builtin_amdgcn_sched_barrier(0);
        }
        region(aB1, bq1);
        if (GG < 35) fence();
    }

    // epilogue: D[(l>>4)*4+r][l&15] per 16x16 fragment
#pragma unroll
    for (int mi = 0; mi < 8; ++mi) {
#pragma unroll
        for (int ni = 0; ni < 4; ++ni) {
#pragma unroll
            for (int r = 0; r < 4; ++r) {
                int m = mt * 256 + wm + mi * 16 + (l >> 4) * 4 + r;
                int co = nt * 256 + wn + ni * 16 + (l & 15);
                out[(((size_t)(b * 4096 + m)) << 9) + co] = acc[mi][ni][r];
            }
        }
    }
}

// ---------------- launch ----------------

extern "C" void kernel_launch(void* const* d_in, const int* in_sizes, int n_in,
                              void* d_out, int out_size, void* d_ws, size_t ws_size,
                              hipStream_t stream) {
    const float* x = (const float*)d_in[0];
    const float* style = (const float*)d_in[1];
    const float* kern = (const float*)d_in[2];
    float* out = (float*)d_out;

    char* ws = (char*)d_ws;
    ushort* xpad = (ushort*)ws;                                // 35,684,352 B
    ushort* wT = (ushort*)(ws + 35684352);                     // 37,748,736 B
    float* Q = (float*)(ws + 35684352 + 37748736);             // 1,048,576 B
    float* sig = (float*)(ws + 35684352 + 37748736 + 1048576); // 16,384 B

    (void)hipFuncSetAttribute((const void*)conv_mfma,
                              hipFuncAttributeMaxDynamicSharedMemorySize, 65536);

    k_q<<<1024, 256, 0, stream>>>(kern, Q);
    k_sigma<<<8, 512, 0, stream>>>(style, Q, sig);
    k_wt<<<dim3(64, 9, 8), 256, 0, stream>>>(kern, style, sig, wT);
    k_xpad<<<8712, 256, 0, stream>>>(x, xpad);
    conv_mfma<<<256, 512, 65536, stream>>>(xpad, wT, out);
}

// Round 7
// 186.539 us; speedup vs baseline: 1.3752x; 1.2865x over previous
//
#include <hip/hip_runtime.h>

typedef __bf16 bf16x8 __attribute__((ext_vector_type(8)));
typedef float f32x4 __attribute__((ext_vector_type(4)));

#define SCALE_F 0.014731391274719738f   /* 1/sqrt(9*512) */
#define SCALE2_F 2.170138888888889e-4f  /* 1/4608 */

__device__ __forceinline__ ushort f2bf(float f) {
    uint x = __float_as_uint(f);
    uint r = (x + 0x7fffu + ((x >> 16) & 1u)) >> 16;
    return (ushort)r;
}

__device__ __forceinline__ void async_cp16(const void* g, void* l) {
    __builtin_amdgcn_global_load_lds(
        (const __attribute__((address_space(1))) void*)g,
        (__attribute__((address_space(3))) void*)l, 16, 0, 0);
}

// ---------------- prep kernels (unchanged) ----------------

__global__ void k_q(const float* __restrict__ kern, float* __restrict__ Q) {
    int idx = blockIdx.x * 256 + threadIdx.x;
    float s = 0.f;
#pragma unroll
    for (int t = 0; t < 9; ++t) { float v = kern[t * 262144 + idx]; s += v * v; }
    Q[idx] = s * SCALE2_F;
}

__global__ void k_sigma(const float* __restrict__ style, const float* __restrict__ Q,
                        float* __restrict__ sig) {
    __shared__ float s2[512];
    int b = blockIdx.x, t = threadIdx.x;
    float s = style[b * 512 + t];
    s2[t] = s * s;
    __syncthreads();
    float acc = 0.f;
#pragma unroll 8
    for (int ci = 0; ci < 512; ++ci) acc += s2[ci] * Q[ci * 512 + t];
    sig[b * 512 + t] = rsqrtf(acc + 1e-8f);
}

__global__ void k_wt(const float* __restrict__ kern, const float* __restrict__ style,
                     const float* __restrict__ sig, ushort* __restrict__ wT) {
    __shared__ ushort tile[64 * 65];
    int b = blockIdx.z, tap = blockIdx.y;
    int ci0 = (blockIdx.x >> 3) << 6, co0 = (blockIdx.x & 7) << 6;
    int t = threadIdx.x;
    int col = t & 63, rq = t >> 6;
#pragma unroll
    for (int r = 0; r < 16; ++r) {
        int ci_l = r * 4 + rq;
        float v = kern[(size_t)(tap * 512 + ci0 + ci_l) * 512 + co0 + col];
        float val = SCALE_F * v * style[b * 512 + ci0 + ci_l] * sig[b * 512 + co0 + col];
        tile[ci_l * 65 + col] = f2bf(val);
    }
    __syncthreads();
#pragma unroll
    for (int r = 0; r < 4; ++r) {
        int q = r * 256 + t;
        int co_l = q >> 4, ciq = (q & 15) << 2;
        uint lo = (uint)tile[ciq * 65 + co_l] | ((uint)tile[(ciq + 1) * 65 + co_l] << 16);
        uint hi = (uint)tile[(ciq + 2) * 65 + co_l] | ((uint)tile[(ciq + 3) * 65 + co_l] << 16);
        *(uint2*)(&wT[((size_t)(b * 9 + tap) * 512 + co0 + co_l) * 512 + ci0 + ciq]) =
            make_uint2(lo, hi);
    }
}

__global__ void k_xpad(const float* __restrict__ x, ushort* __restrict__ xp) {
    int idx = blockIdx.x * 256 + threadIdx.x;
    int pos = idx >> 6, e = idx & 63;
    int b = pos / 4356, rem = pos - b * 4356;
    int hp = rem / 66, wp = rem - hp * 66;
    int ci0 = e << 3;
    uint4 o = make_uint4(0u, 0u, 0u, 0u);
    if (hp >= 1 && hp <= 64 && wp >= 1 && wp <= 64) {
        const float4* s =
            (const float4*)(x + (((size_t)(b * 4096 + (hp - 1) * 64 + (wp - 1))) << 9) + ci0);
        float4 v0 = s[0], v1 = s[1];
        o.x = (uint)f2bf(v0.x) | ((uint)f2bf(v0.y) << 16);
        o.y = (uint)f2bf(v0.z) | ((uint)f2bf(v0.w) << 16);
        o.z = (uint)f2bf(v1.x) | ((uint)f2bf(v1.y) << 16);
        o.w = (uint)f2bf(v1.z) | ((uint)f2bf(v1.w) << 16);
    }
    *(uint4*)(xp + (((size_t)pos) << 9) + ci0) = o;
}

// ---------------- main conv: 256x256 tile, BK=64, 8 waves ----------------
// R7 = R4 + read-ahead register double-buffer for A fragments: phase q+1's
// ds_reads are issued BEFORE phase q's MFMA cluster, so the LDS pipe streams
// next-phase fragments while the matrix pipe runs (overlap instead of sum).
// One barrier + vmcnt(0) per K-tile; A+B double-buffered in 128KB LDS.
__global__ __launch_bounds__(512, 2) void conv_mfma(const ushort* __restrict__ xpad,
                                                    const ushort* __restrict__ wT,
                                                    float* __restrict__ out) {
    extern __shared__ char lds[];

    const int wg = blockIdx.x;                      // 0..255
    const int swz = (wg & 7) * 32 + (wg >> 3);      // bijective XCD swizzle
    const int mt = swz & 15;
    const int nt = (swz >> 4) & 1;
    const int b = swz >> 5;

    const int tid = threadIdx.x;
    const int l = tid & 63, wv = tid >> 6;
    const int wm = (wv >> 2) * 128;
    const int wn = (wv & 3) * 64;
    const int ha = wv >> 2;          // A half this wave reads
    const int hb = (wv & 3) >> 1;    // B half this wave reads

    // staging geometry: lane l covers row (l>>3) of an 8-row group, stored chunk l&7
    const int rl = l >> 3;
    const int g = (l & 7) ^ rl;      // data chunk pre-swizzle
    const ushort* baseA[2][2];
    const ushort* baseB[2][2];
    int ldsoff[2][2];
#pragma unroll
    for (int h = 0; h < 2; ++h)
#pragma unroll
        for (int i = 0; i < 2; ++i) {
            int rloc = wv * 16 + i * 8 + rl;
            int R = h * 128 + rloc;
            baseA[h][i] = xpad + ((size_t)((b * 66 + mt * 4 + (R >> 6)) * 66 + (R & 63))) * 512 + g * 8;
            baseB[h][i] = wT + ((size_t)(b * 9 * 512 + nt * 256 + R)) * 512 + g * 8;
            ldsoff[h][i] = (h * 128 + wv * 16 + i * 8) * 128;
        }

    auto offA = [](int t) -> int {
        int tap = t >> 3;
        int ky = (tap * 11) >> 5;
        int kx = tap - ky * 3;
        return (ky * 66 + kx) * 512 + ((t & 7) << 6);
    };
    auto offB = [](int t) -> int { return (t >> 3) * 262144 + ((t & 7) << 6); };

    auto stageAll = [&](int t, int buf) {
        int oA = offA(t), oB = offB(t);
        char* Ab = lds + buf * 32768;
        char* Bb = lds + 65536 + buf * 32768;
#pragma unroll
        for (int h = 0; h < 2; ++h)
#pragma unroll
            for (int i = 0; i < 2; ++i)
                async_cp16(baseA[h][i] + oA, Ab + ldsoff[h][i]);
#pragma unroll
        for (int h = 0; h < 2; ++h)
#pragma unroll
            for (int i = 0; i < 2; ++i)
                async_cp16(baseB[h][i] + oB, Bb + ldsoff[h][i]);
    };

    f32x4 acc[8][4];
#pragma unroll
    for (int mi = 0; mi < 8; ++mi)
#pragma unroll
        for (int ni = 0; ni < 4; ++ni) acc[mi][ni] = (f32x4){0.f, 0.f, 0.f, 0.f};

    // prologue: stage K-tile 0 into buf 0, drain, barrier
    stageAll(0, 0);
    asm volatile("s_waitcnt vmcnt(0)" ::: "memory");
    __builtin_amdgcn_sched_barrier(0);
    __builtin_amdgcn_s_barrier();
    __builtin_amdgcn_sched_barrier(0);

    const int frow = l & 15;
    const int fchunk_base = l >> 4;   // 0..3
    const int fxor = l & 7;

#pragma unroll 1
    for (int G = 0; G < 72; ++G) {
        const int cur = G & 1;
        const char* aB = lds + cur * 32768 + ha * 16384;
        const char* bB = lds + 65536 + cur * 32768 + hb * 16384;

        // issue next tile's staging first (earliest VMEM issue, full region of cover)
        if (G <= 70) stageAll(G + 1, cur ^ 1);

        // B fragments for the whole K-tile (register-resident)
        bf16x8 bq[4][2];
#pragma unroll
        for (int kk = 0; kk < 2; ++kk)
#pragma unroll
            for (int ni = 0; ni < 4; ++ni) {
                int r = (wn & 64) + ni * 16 + frow;
                bq[ni][kk] = *(const bf16x8*)(bB + r * 128 +
                                              (((kk * 4 + fchunk_base) ^ fxor) * 16));
            }

        // A fragments: double-buffered by phase parity; read phase q+1 before MFMA(q)
        bf16x8 aq[2][2][2];   // [parity][m2][kk]  (static indices after unroll)
#pragma unroll
        for (int m2 = 0; m2 < 2; ++m2)
#pragma unroll
            for (int kk = 0; kk < 2; ++kk) {
                int r = m2 * 16 + frow;   // phase 0 rows
                aq[0][m2][kk] = *(const bf16x8*)(aB + r * 128 +
                                                 (((kk * 4 + fchunk_base) ^ fxor) * 16));
            }

#pragma unroll
        for (int q = 0; q < 4; ++q) {
            if (q < 3) {
#pragma unroll
                for (int m2 = 0; m2 < 2; ++m2)
#pragma unroll
                    for (int kk = 0; kk < 2; ++kk) {
                        int r = (2 * (q + 1) + m2) * 16 + frow;
                        aq[(q + 1) & 1][m2][kk] =
                            *(const bf16x8*)(aB + r * 128 +
                                             (((kk * 4 + fchunk_base) ^ fxor) * 16));
                    }
            }
            __builtin_amdgcn_s_setprio(1);
#pragma unroll
            for (int kk = 0; kk < 2; ++kk)
#pragma unroll
                for (int ni = 0; ni < 4; ++ni)
#pragma unroll
                    for (int m2 = 0; m2 < 2; ++m2)
                        acc[2 * q + m2][ni] = __builtin_amdgcn_mfma_f32_16x16x32_bf16(
                            aq[q & 1][m2][kk], bq[ni][kk], acc[2 * q + m2][ni], 0, 0, 0);
            __builtin_amdgcn_s_setprio(0);
        }

        // region end: drain this region's stages, barrier (skip after last tile)
        if (G <= 70) {
            asm volatile("s_waitcnt vmcnt(0)" ::: "memory");
            __builtin_amdgcn_sched_barrier(0);
            __builtin_amdgcn_s_barrier();
            __builtin_amdgcn_sched_barrier(0);
        }
    }

    // epilogue: D[(l>>4)*4+r][l&15] per 16x16 fragment
#pragma unroll
    for (int mi = 0; mi < 8; ++mi) {
#pragma unroll
        for (int ni = 0; ni < 4; ++ni) {
#pragma unroll
            for (int r = 0; r < 4; ++r) {
                int m = mt * 256 + wm + mi * 16 + (l >> 4) * 4 + r;
                int co = nt * 256 + wn + ni * 16 + (l & 15);
                out[(((size_t)(b * 4096 + m)) << 9) + co] = acc[mi][ni][r];
            }
        }
    }
}

// ---------------- launch ----------------

extern "C" void kernel_launch(void* const* d_in, const int* in_sizes, int n_in,
                              void* d_out, int out_size, void* d_ws, size_t ws_size,
                              hipStream_t stream) {
    const float* x = (const float*)d_in[0];
    const float* style = (const float*)d_in[1];
    const float* kern = (const float*)d_in[2];
    float* out = (float*)d_out;

    char* ws = (char*)d_ws;
    ushort* xpad = (ushort*)ws;                                // 35,684,352 B
    ushort* wT = (ushort*)(ws + 35684352);                     // 37,748,736 B
    float* Q = (float*)(ws + 35684352 + 37748736);             // 1,048,576 B
    float* sig = (float*)(ws + 35684352 + 37748736 + 1048576); // 16,384 B

    (void)hipFuncSetAttribute((const void*)conv_mfma,
                              hipFuncAttributeMaxDynamicSharedMemorySize, 131072);

    k_q<<<1024, 256, 0, stream>>>(kern, Q);
    k_sigma<<<8, 512, 0, stream>>>(style, Q, sig);
    k_wt<<<dim3(64, 9, 8), 256, 0, stream>>>(kern, style, sig, wT);
    k_xpad<<<8712, 256, 0, stream>>>(x, xpad);
    conv_mfma<<<256, 512, 131072, stream>>>(xpad, wT, out);
}